// Round 16
// baseline (400.765 us; speedup 1.0000x reference)
//
#include <hip/hip_runtime.h>

// ---------------------------------------------------------------------------
// GraphSAGE 2-layer (mean aggr) + linear classifier, fp32, N=100K, D=64, E=16N
// R13 (6th submit; five consecutive GPUAcquisitionTimeouts — infra, kernel
//  never executed): fuse aggregate+GEMM per layer; kill m1.
//  R12 was neutral => build writes were never the hidden cost. Accounting:
//  agg 116 (measured) + gemm ~30 + build ~50 leaves ~130us in launch gaps +
//  the m1 round-trip (102MB of pure intermediate traffic). Fix: one kernel
//  per layer: 512thr/128-node tile; phase A aggregates 16 nodes/wave into
//  LDS Mt directly (m1 never exists), then R10's register-tiled GEMM runs
//  from LDS (Mt@Wl, restage Mt<-X, +X@Wr). 49.7KB LDS -> 3 blocks/CU ->
//  24 waves/CU -> 384 outstanding gathers/CU (vs 300) so the gather side
//  should not regress (R6 trap avoided by keeping 16-deep pipelines).
//  Also folds add_offs into bucket_place/csr_bucket. Kernels 10 -> 7.
// Build (bucket radix, atomic-free) otherwise unchanged from R12.
// ---------------------------------------------------------------------------

#define SCAN_BS 1024
#define BUCKET_BITS 9
#define BUCKET_NODES 512        // nodes per bucket
#define NBUCK_MAX 256           // >= B = ceil(100000/512) = 196
#define EPB 8192                // edges per block in hist/place passes
#define STAGE_CAP 10240         // bucket edges: mean 8192, sigma ~90

// --- K1: per-block bucket histogram -> counts[k * NB + b] (bucket-major) ---
__global__ void __launch_bounds__(256) bucket_hist_kernel(const int* __restrict__ dst,
                                                          int* __restrict__ counts,
                                                          int ne, int B, int NB) {
  __shared__ int hist[NBUCK_MAX];
  for (int k = threadIdx.x; k < B; k += 256) hist[k] = 0;
  __syncthreads();
  int base = blockIdx.x * EPB;
#pragma unroll 4
  for (int i = 0; i < EPB / 256; ++i) {
    int e = base + i * 256 + threadIdx.x;
    if (e < ne) atomicAdd(&hist[dst[e] >> BUCKET_BITS], 1);
  }
  __syncthreads();
  for (int k = threadIdx.x; k < B; k += 256) counts[k * NB + blockIdx.x] = hist[k];
}

// --- 2-level scan (in-place exclusive over counts) ---
__device__ __forceinline__ int block_scan_inclusive_1024(int v, int* wsums) {
  int lane = threadIdx.x & 63;
  int wid = threadIdx.x >> 6;
  int s = v;
#pragma unroll
  for (int off = 1; off < 64; off <<= 1) {
    int t = __shfl_up(s, off);
    if (lane >= off) s += t;
  }
  if (lane == 63) wsums[wid] = s;
  __syncthreads();
  if (wid == 0) {
    int ws = (lane < 16) ? wsums[lane] : 0;
#pragma unroll
    for (int off = 1; off < 16; off <<= 1) {
      int t = __shfl_up(ws, off);
      if (lane >= off) ws += t;
    }
    if (lane < 16) wsums[lane] = ws;
  }
  __syncthreads();
  if (wid > 0) s += wsums[wid - 1];
  return s;
}

__device__ __forceinline__ int block_scan_inclusive_256(int v, int* wsums4) {
  int lane = threadIdx.x & 63;
  int wid = threadIdx.x >> 6;  // 0..3
  int s = v;
#pragma unroll
  for (int off = 1; off < 64; off <<= 1) {
    int t = __shfl_up(s, off);
    if (lane >= off) s += t;
  }
  if (lane == 63) wsums4[wid] = s;
  __syncthreads();
  if (wid == 0) {
    int ws = (lane < 4) ? wsums4[lane] : 0;
#pragma unroll
    for (int off = 1; off < 4; off <<= 1) {
      int t = __shfl_up(ws, off);
      if (lane >= off) ws += t;
    }
    if (lane < 4) wsums4[lane] = ws;
  }
  __syncthreads();
  if (wid > 0) s += wsums4[wid - 1];
  return s;
}

__global__ void __launch_bounds__(SCAN_BS) scan_a_inplace_kernel(int* __restrict__ data,
                                                                 int* __restrict__ bsums,
                                                                 int S) {
  __shared__ int wsums[16];
  int i = blockIdx.x * SCAN_BS + threadIdx.x;
  int v = (i < S) ? data[i] : 0;
  int inc = block_scan_inclusive_1024(v, wsums);
  if (i < S) data[i] = inc - v;  // exclusive, block-local
  if (threadIdx.x == SCAN_BS - 1) bsums[blockIdx.x] = inc;
}

__global__ void __launch_bounds__(SCAN_BS) scan_b_kernel(const int* __restrict__ bsums,
                                                         int* __restrict__ boffs, int nb) {
  __shared__ int wsums[16];
  int v = ((int)threadIdx.x < nb) ? bsums[threadIdx.x] : 0;
  int inc = block_scan_inclusive_1024(v, wsums);
  if ((int)threadIdx.x < nb) boffs[threadIdx.x] = inc - v;
  if ((int)threadIdx.x == nb - 1) boffs[nb] = inc;
}

// --- K3: placement into bucket-grouped arr; LDS cursors; boffs folded in ---
__global__ void __launch_bounds__(256) bucket_place_kernel(const int* __restrict__ src,
                                                           const int* __restrict__ dst,
                                                           const int* __restrict__ counts,
                                                           const int* __restrict__ boffs,
                                                           int* __restrict__ arr,
                                                           int ne, int B, int NB) {
  __shared__ int cur[NBUCK_MAX];
  for (int k = threadIdx.x; k < B; k += 256) {
    int idx = k * NB + blockIdx.x;
    cur[k] = counts[idx] + boffs[idx >> 10];
  }
  __syncthreads();
  int base = blockIdx.x * EPB;
#pragma unroll 4
  for (int i = 0; i < EPB / 256; ++i) {
    int e = base + i * 256 + threadIdx.x;
    if (e < ne) {
      int d = dst[e];
      int k = d >> BUCKET_BITS;
      int pos = atomicAdd(&cur[k], 1);  // LDS atomic, absolute output slot
      arr[pos] = (src[e] << BUCKET_BITS) | (d & (BUCKET_NODES - 1));
    }
  }
}

// --- K4: per-bucket node-level CSR; LDS-staged coalesced col writes --------
__global__ void __launch_bounds__(256) csr_bucket_kernel(const int* __restrict__ arr,
                                                         const int* __restrict__ counts,
                                                         const int* __restrict__ boffs,
                                                         int* __restrict__ row_ptr,
                                                         int* __restrict__ col,
                                                         int n, int ne, int B, int NB) {
  __shared__ int hist[BUCKET_NODES];
  __shared__ int cur[BUCKET_NODES];
  __shared__ int stage[STAGE_CAP];
  __shared__ int wsums4[4];
  int k = blockIdx.x;
  int tid = threadIdx.x;
  int i0 = k * NB;
  int start = counts[i0] + boffs[i0 >> 10];
  int end;
  if (k + 1 < B) {
    int i1 = (k + 1) * NB;
    end = counts[i1] + boffs[i1 >> 10];
  } else {
    end = ne;
  }
  int size = end - start;
  hist[tid] = 0;
  hist[tid + 256] = 0;
  __syncthreads();
  for (int e = start + tid; e < end; e += 256)
    atomicAdd(&hist[arr[e] & (BUCKET_NODES - 1)], 1);
  __syncthreads();
  // exclusive scan of 512 counters: 2 per thread
  int v0 = hist[tid * 2], v1 = hist[tid * 2 + 1];
  int inc = block_scan_inclusive_256(v0 + v1, wsums4);
  int e0 = inc - (v0 + v1);
  {
    int node0 = k * BUCKET_NODES;
    cur[tid * 2] = e0;
    cur[tid * 2 + 1] = e0 + v0;
    if (node0 + tid * 2 < n) row_ptr[node0 + tid * 2] = start + e0;
    if (node0 + tid * 2 + 1 < n) row_ptr[node0 + tid * 2 + 1] = start + e0 + v0;
  }
  if (k == B - 1 && tid == 0) row_ptr[n] = ne;
  __syncthreads();
  for (int e = start + tid; e < end; e += 256) {
    int p = arr[e];
    int pos = atomicAdd(&cur[p & (BUCKET_NODES - 1)], 1);  // bucket-local slot
    int s = p >> BUCKET_BITS;
    if (pos < STAGE_CAP) stage[pos] = s;
    else col[start + pos] = s;  // statistical never (cap = mean + 22 sigma)
  }
  __syncthreads();
  int lim = (size < STAGE_CAP) ? size : STAGE_CAP;
  for (int i = tid; i < lim; i += 256) col[start + i] = stage[i];  // coalesced
}

// ---- fused aggregate + register-tiled GEMM --------------------------------
// 512 thr = 8 waves; tile 128 nodes. Phase A: wave w aggregates nodes
// w*16..w*16+15 into Mt (16-deep gather pipeline, wave-uniform col s_loads).
// GEMM: 16tx x 32ty, TM=4 rows, TN=4 cols; K=128 as two 64-phases, Mt
// restaged with X between. 49.7KB LDS -> 3 blocks/CU = 24 waves/CU.

#define FBM 128
#define FTHREADS 512

__device__ __forceinline__ void fused_agg_phase(const float* __restrict__ X,
                                                const int* __restrict__ row_ptr,
                                                const int* __restrict__ col,
                                                float (&Mt)[FBM][65],
                                                int node0, int n, int w, int lane) {
  for (int i = 0; i < 16; ++i) {
    int row = w * 16 + i;
    int m = node0 + row;  // wave-uniform
    float mean = 0.f;
    if (m < n) {
      int start = row_ptr[m];
      int end = row_ptr[m + 1];
      float a[16];
#pragma unroll
      for (int j = 0; j < 16; ++j) a[j] = 0.f;
      int e = start;
      for (; e + 16 <= end; e += 16) {
        int c[16];
#pragma unroll
        for (int j = 0; j < 16; ++j) c[j] = col[e + j];
#pragma unroll
        for (int j = 0; j < 16; ++j) a[j] += X[(size_t)c[j] * 64 + lane];
      }
      for (; e < end; ++e) a[0] += X[(size_t)col[e] * 64 + lane];
#pragma unroll
      for (int s = 8; s > 0; s >>= 1)
#pragma unroll
        for (int j = 0; j < s; ++j) a[j] += a[j + s];
      int d = end - start;
      mean = a[0] / (float)((d > 0) ? d : 1);
    }
    Mt[row][lane] = mean;
  }
}

__device__ __forceinline__ void fused_gemm_accum(float (&Mt)[FBM][65],
                                                 float (&Ws)[64][64],
                                                 float4 (&acc)[4], int tx, int ty) {
#pragma unroll 4
  for (int k = 0; k < 64; ++k) {
    float4 w4 = *(const float4*)&Ws[k][tx * 4];
    float a0 = Mt[ty * 4 + 0][k];
    float a1 = Mt[ty * 4 + 1][k];
    float a2 = Mt[ty * 4 + 2][k];
    float a3 = Mt[ty * 4 + 3][k];
    acc[0].x = fmaf(a0, w4.x, acc[0].x);
    acc[0].y = fmaf(a0, w4.y, acc[0].y);
    acc[0].z = fmaf(a0, w4.z, acc[0].z);
    acc[0].w = fmaf(a0, w4.w, acc[0].w);
    acc[1].x = fmaf(a1, w4.x, acc[1].x);
    acc[1].y = fmaf(a1, w4.y, acc[1].y);
    acc[1].z = fmaf(a1, w4.z, acc[1].z);
    acc[1].w = fmaf(a1, w4.w, acc[1].w);
    acc[2].x = fmaf(a2, w4.x, acc[2].x);
    acc[2].y = fmaf(a2, w4.y, acc[2].y);
    acc[2].z = fmaf(a2, w4.z, acc[2].z);
    acc[2].w = fmaf(a2, w4.w, acc[2].w);
    acc[3].x = fmaf(a3, w4.x, acc[3].x);
    acc[3].y = fmaf(a3, w4.y, acc[3].y);
    acc[3].z = fmaf(a3, w4.z, acc[3].z);
    acc[3].w = fmaf(a3, w4.w, acc[3].w);
  }
}

__device__ __forceinline__ void fused_stage_w(const float* __restrict__ W,
                                              float (&Ws)[64][64], int t) {
#pragma unroll
  for (int i = 0; i < 2; ++i) {
    int f4 = i * FTHREADS + t;  // 1024 float4 over [64][16]
    int k = f4 >> 4, c4 = f4 & 15;
    *(float4*)&Ws[k][c4 * 4] = ((const float4*)W)[f4];
  }
}

__device__ __forceinline__ void fused_stage_x(const float* __restrict__ X,
                                              float (&Mt)[FBM][65],
                                              int node0, int n, int t) {
#pragma unroll
  for (int i = 0; i < 4; ++i) {
    int f4 = i * FTHREADS + t;  // 2048 float4 over [128][16]
    int r = f4 >> 4, c4 = f4 & 15;
    int nd = node0 + r;
    float4 v = make_float4(0.f, 0.f, 0.f, 0.f);
    if (nd < n) v = ((const float4*)(X + (size_t)nd * 64))[c4];
    Mt[r][c4 * 4 + 0] = v.x;
    Mt[r][c4 * 4 + 1] = v.y;
    Mt[r][c4 * 4 + 2] = v.z;
    Mt[r][c4 * 4 + 3] = v.w;
  }
}

// H = relu(mean(X[neigh]) @ Wl + b + X @ Wr)
__global__ void __launch_bounds__(FTHREADS) agg_gemm_relu_kernel(
    const float* __restrict__ X, const int* __restrict__ row_ptr,
    const int* __restrict__ col, const float* __restrict__ Wl,
    const float* __restrict__ bias, const float* __restrict__ Wr,
    float* __restrict__ H, int n) {
  __shared__ float Mt[FBM][65];
  __shared__ float Ws[64][64];
  int t = threadIdx.x;
  int lane = t & 63;
  int w = __builtin_amdgcn_readfirstlane(t >> 6);  // 0..7
  int node0 = blockIdx.x * FBM;
  fused_agg_phase(X, row_ptr, col, Mt, node0, n, w, lane);
  fused_stage_w(Wl, Ws, t);
  __syncthreads();
  int tx = t & 15, ty = t >> 4;  // ty 0..31
  float4 bv = *(const float4*)(bias + tx * 4);
  float4 acc[4];
#pragma unroll
  for (int m = 0; m < 4; ++m) acc[m] = bv;
  fused_gemm_accum(Mt, Ws, acc, tx, ty);
  __syncthreads();
  fused_stage_x(X, Mt, node0, n, t);
  fused_stage_w(Wr, Ws, t);
  __syncthreads();
  fused_gemm_accum(Mt, Ws, acc, tx, ty);
#pragma unroll
  for (int m = 0; m < 4; ++m) {
    int nd = node0 + ty * 4 + m;
    if (nd < n) {
      float4 v;
      v.x = fmaxf(acc[m].x, 0.f);
      v.y = fmaxf(acc[m].y, 0.f);
      v.z = fmaxf(acc[m].z, 0.f);
      v.w = fmaxf(acc[m].w, 0.f);
      ((float4*)(H + (size_t)nd * 64))[tx] = v;
    }
  }
}

// out = (mean(Hn[neigh]) @ Wl + b + Hn @ Wr) @ Wc + bc; h2 never materialized.
__global__ void __launch_bounds__(FTHREADS) agg_gemm_cls_kernel(
    const float* __restrict__ X, const int* __restrict__ row_ptr,
    const int* __restrict__ col, const float* __restrict__ Wl,
    const float* __restrict__ bias, const float* __restrict__ Wr,
    const float* __restrict__ Wc, const float* __restrict__ bc,
    float* __restrict__ outp, int n) {
  __shared__ float Mt[FBM][65];
  __shared__ float Ws[64][64];
  int t = threadIdx.x;
  int lane = t & 63;
  int w = __builtin_amdgcn_readfirstlane(t >> 6);
  int node0 = blockIdx.x * FBM;
  fused_agg_phase(X, row_ptr, col, Mt, node0, n, w, lane);
  fused_stage_w(Wl, Ws, t);
  __syncthreads();
  int tx = t & 15, ty = t >> 4;
  float4 bv = *(const float4*)(bias + tx * 4);
  float4 acc[4];
#pragma unroll
  for (int m = 0; m < 4; ++m) acc[m] = bv;
  fused_gemm_accum(Mt, Ws, acc, tx, ty);
  __syncthreads();
  fused_stage_x(X, Mt, node0, n, t);
  fused_stage_w(Wr, Ws, t);
  __syncthreads();
  fused_gemm_accum(Mt, Ws, acc, tx, ty);
  // classifier: per-thread partial dots over its 4 j's, shfl_xor over tx
  float2 wc0 = *(const float2*)(Wc + (tx * 4 + 0) * 2);
  float2 wc1 = *(const float2*)(Wc + (tx * 4 + 1) * 2);
  float2 wc2 = *(const float2*)(Wc + (tx * 4 + 2) * 2);
  float2 wc3 = *(const float2*)(Wc + (tx * 4 + 3) * 2);
  float b0 = bc[0], b1 = bc[1];
#pragma unroll
  for (int m = 0; m < 4; ++m) {
    float p0 = acc[m].x * wc0.x + acc[m].y * wc1.x + acc[m].z * wc2.x + acc[m].w * wc3.x;
    float p1 = acc[m].x * wc0.y + acc[m].y * wc1.y + acc[m].z * wc2.y + acc[m].w * wc3.y;
#pragma unroll
    for (int off = 1; off < 16; off <<= 1) {  // lane = (ty&3)*16 + tx
      p0 += __shfl_xor(p0, off);
      p1 += __shfl_xor(p1, off);
    }
    if (tx == 0) {
      int nd = node0 + ty * 4 + m;
      if (nd < n) {
        float2 o;
        o.x = p0 + b0;
        o.y = p1 + b1;
        *(float2*)(outp + (size_t)nd * 2) = o;
      }
    }
  }
}

extern "C" void kernel_launch(void* const* d_in, const int* in_sizes, int n_in,
                              void* d_out, int out_size, void* d_ws, size_t ws_size,
                              hipStream_t stream) {
  const float* x   = (const float*)d_in[0];
  const int*   ei  = (const int*)d_in[1];
  const float* W1l = (const float*)d_in[2];
  const float* b1  = (const float*)d_in[3];
  const float* W1r = (const float*)d_in[4];
  const float* W2l = (const float*)d_in[5];
  const float* b2  = (const float*)d_in[6];
  const float* W2r = (const float*)d_in[7];
  const float* Wc  = (const float*)d_in[8];
  const float* bc  = (const float*)d_in[9];
  float* out = (float*)d_out;

  const int n  = in_sizes[0] / 64;   // 100000
  const int ne = in_sizes[1] / 2;    // 1600000
  const int* src = ei;
  const int* dst = ei + ne;

  const int B  = (n + BUCKET_NODES - 1) >> BUCKET_BITS;  // 196
  const int NB = (ne + EPB - 1) / EPB;                   // 196
  const int S  = B * NB;                                 // 38416
  const int nsb = (S + SCAN_BS - 1) / SCAN_BS;           // 38 (<=1024)

  char* ws = (char*)d_ws;
  size_t off = 0;
  auto carve = [&](size_t bytes) -> void* {
    void* p = ws + off;
    off += (bytes + 255) & ~(size_t)255;
    return p;
  };
  int* counts  = (int*)carve((size_t)S * 4);
  int* bsums   = (int*)carve((size_t)(nsb + 1) * 4);
  int* boffs   = (int*)carve((size_t)(nsb + 1) * 4);
  int* col     = (int*)carve((size_t)ne * 4);
  int* row_ptr = (int*)carve((size_t)(n + 1) * 4);
  int* arr     = (int*)carve((size_t)ne * 4);
  float* h     = (float*)carve((size_t)n * 64 * 4);
  (void)ws_size;

  bucket_hist_kernel<<<NB, 256, 0, stream>>>(dst, counts, ne, B, NB);
  scan_a_inplace_kernel<<<nsb, SCAN_BS, 0, stream>>>(counts, bsums, S);
  scan_b_kernel<<<1, SCAN_BS, 0, stream>>>(bsums, boffs, nsb);
  bucket_place_kernel<<<NB, 256, 0, stream>>>(src, dst, counts, boffs, arr, ne, B, NB);
  csr_bucket_kernel<<<B, 256, 0, stream>>>(arr, counts, boffs, row_ptr, col, n, ne, B, NB);

  const int ftiles = (n + FBM - 1) / FBM;  // 782
  agg_gemm_relu_kernel<<<ftiles, FTHREADS, 0, stream>>>(x, row_ptr, col, W1l, b1, W1r, h, n);
  agg_gemm_cls_kernel<<<ftiles, FTHREADS, 0, stream>>>(h, row_ptr, col, W2l, b2, W2r, Wc, bc, out, n);
}

// Round 17
// 326.949 us; speedup vs baseline: 1.2258x; 1.2258x over previous
//
#include <hip/hip_runtime.h>

// ---------------------------------------------------------------------------
// GraphSAGE 2-layer (mean aggr) + linear classifier, fp32, N=100K, D=64, E=16N
// R14: revert R13 fusion (measured 400.8us: fused kernels 138us each, occ 40%,
//  HBM 1.59 vs 3.6 TB/s split -- barrier-coupled gather loses the independent
//  wave slack; falsifier >=85us fired). Back to R12's split structure
//  (measured 329.7us), keeping R13's validated add_offs fold (-1 dispatch).
//  R13 also proved the ~130us residual is build+gaps, NOT m1 traffic
//  (residual unchanged with m1 eliminated). Aggregate is L3-gather-bound
//  (R6 bucket alternative 717us; R11 counters 3.6TB/s, near floor).
// ---------------------------------------------------------------------------

#define SCAN_BS 1024
#define BUCKET_BITS 9
#define BUCKET_NODES 512        // nodes per bucket
#define NBUCK_MAX 256           // >= B = ceil(100000/512) = 196
#define EPB 8192                // edges per block in hist/place passes
#define STAGE_CAP 10240         // bucket edges: mean 8192, sigma ~90

// --- K1: per-block bucket histogram -> counts[k * NB + b] (bucket-major) ---
__global__ void __launch_bounds__(256) bucket_hist_kernel(const int* __restrict__ dst,
                                                          int* __restrict__ counts,
                                                          int ne, int B, int NB) {
  __shared__ int hist[NBUCK_MAX];
  for (int k = threadIdx.x; k < B; k += 256) hist[k] = 0;
  __syncthreads();
  int base = blockIdx.x * EPB;
#pragma unroll 4
  for (int i = 0; i < EPB / 256; ++i) {
    int e = base + i * 256 + threadIdx.x;
    if (e < ne) atomicAdd(&hist[dst[e] >> BUCKET_BITS], 1);
  }
  __syncthreads();
  for (int k = threadIdx.x; k < B; k += 256) counts[k * NB + blockIdx.x] = hist[k];
}

// --- 2-level scan (in-place exclusive over counts) ---
__device__ __forceinline__ int block_scan_inclusive_1024(int v, int* wsums) {
  int lane = threadIdx.x & 63;
  int wid = threadIdx.x >> 6;
  int s = v;
#pragma unroll
  for (int off = 1; off < 64; off <<= 1) {
    int t = __shfl_up(s, off);
    if (lane >= off) s += t;
  }
  if (lane == 63) wsums[wid] = s;
  __syncthreads();
  if (wid == 0) {
    int ws = (lane < 16) ? wsums[lane] : 0;
#pragma unroll
    for (int off = 1; off < 16; off <<= 1) {
      int t = __shfl_up(ws, off);
      if (lane >= off) ws += t;
    }
    if (lane < 16) wsums[lane] = ws;
  }
  __syncthreads();
  if (wid > 0) s += wsums[wid - 1];
  return s;
}

__device__ __forceinline__ int block_scan_inclusive_256(int v, int* wsums4) {
  int lane = threadIdx.x & 63;
  int wid = threadIdx.x >> 6;  // 0..3
  int s = v;
#pragma unroll
  for (int off = 1; off < 64; off <<= 1) {
    int t = __shfl_up(s, off);
    if (lane >= off) s += t;
  }
  if (lane == 63) wsums4[wid] = s;
  __syncthreads();
  if (wid == 0) {
    int ws = (lane < 4) ? wsums4[lane] : 0;
#pragma unroll
    for (int off = 1; off < 4; off <<= 1) {
      int t = __shfl_up(ws, off);
      if (lane >= off) ws += t;
    }
    if (lane < 4) wsums4[lane] = ws;
  }
  __syncthreads();
  if (wid > 0) s += wsums4[wid - 1];
  return s;
}

__global__ void __launch_bounds__(SCAN_BS) scan_a_inplace_kernel(int* __restrict__ data,
                                                                 int* __restrict__ bsums,
                                                                 int S) {
  __shared__ int wsums[16];
  int i = blockIdx.x * SCAN_BS + threadIdx.x;
  int v = (i < S) ? data[i] : 0;
  int inc = block_scan_inclusive_1024(v, wsums);
  if (i < S) data[i] = inc - v;  // exclusive, block-local
  if (threadIdx.x == SCAN_BS - 1) bsums[blockIdx.x] = inc;
}

__global__ void __launch_bounds__(SCAN_BS) scan_b_kernel(const int* __restrict__ bsums,
                                                         int* __restrict__ boffs, int nb) {
  __shared__ int wsums[16];
  int v = ((int)threadIdx.x < nb) ? bsums[threadIdx.x] : 0;
  int inc = block_scan_inclusive_1024(v, wsums);
  if ((int)threadIdx.x < nb) boffs[threadIdx.x] = inc - v;
  if ((int)threadIdx.x == nb - 1) boffs[nb] = inc;
}

// --- K3: placement into bucket-grouped arr; LDS cursors; boffs folded in ---
__global__ void __launch_bounds__(256) bucket_place_kernel(const int* __restrict__ src,
                                                           const int* __restrict__ dst,
                                                           const int* __restrict__ counts,
                                                           const int* __restrict__ boffs,
                                                           int* __restrict__ arr,
                                                           int ne, int B, int NB) {
  __shared__ int cur[NBUCK_MAX];
  for (int k = threadIdx.x; k < B; k += 256) {
    int idx = k * NB + blockIdx.x;
    cur[k] = counts[idx] + boffs[idx >> 10];
  }
  __syncthreads();
  int base = blockIdx.x * EPB;
#pragma unroll 4
  for (int i = 0; i < EPB / 256; ++i) {
    int e = base + i * 256 + threadIdx.x;
    if (e < ne) {
      int d = dst[e];
      int k = d >> BUCKET_BITS;
      int pos = atomicAdd(&cur[k], 1);  // LDS atomic, absolute output slot
      arr[pos] = (src[e] << BUCKET_BITS) | (d & (BUCKET_NODES - 1));
    }
  }
}

// --- K4: per-bucket node-level CSR; LDS-staged coalesced col writes --------
__global__ void __launch_bounds__(256) csr_bucket_kernel(const int* __restrict__ arr,
                                                         const int* __restrict__ counts,
                                                         const int* __restrict__ boffs,
                                                         int* __restrict__ row_ptr,
                                                         int* __restrict__ col,
                                                         int n, int ne, int B, int NB) {
  __shared__ int hist[BUCKET_NODES];
  __shared__ int cur[BUCKET_NODES];
  __shared__ int stage[STAGE_CAP];
  __shared__ int wsums4[4];
  int k = blockIdx.x;
  int tid = threadIdx.x;
  int i0 = k * NB;
  int start = counts[i0] + boffs[i0 >> 10];
  int end;
  if (k + 1 < B) {
    int i1 = (k + 1) * NB;
    end = counts[i1] + boffs[i1 >> 10];
  } else {
    end = ne;
  }
  int size = end - start;
  hist[tid] = 0;
  hist[tid + 256] = 0;
  __syncthreads();
  for (int e = start + tid; e < end; e += 256)
    atomicAdd(&hist[arr[e] & (BUCKET_NODES - 1)], 1);
  __syncthreads();
  // exclusive scan of 512 counters: 2 per thread
  int v0 = hist[tid * 2], v1 = hist[tid * 2 + 1];
  int inc = block_scan_inclusive_256(v0 + v1, wsums4);
  int e0 = inc - (v0 + v1);
  {
    int node0 = k * BUCKET_NODES;
    cur[tid * 2] = e0;
    cur[tid * 2 + 1] = e0 + v0;
    if (node0 + tid * 2 < n) row_ptr[node0 + tid * 2] = start + e0;
    if (node0 + tid * 2 + 1 < n) row_ptr[node0 + tid * 2 + 1] = start + e0 + v0;
  }
  if (k == B - 1 && tid == 0) row_ptr[n] = ne;
  __syncthreads();
  for (int e = start + tid; e < end; e += 256) {
    int p = arr[e];
    int pos = atomicAdd(&cur[p & (BUCKET_NODES - 1)], 1);  // bucket-local slot
    int s = p >> BUCKET_BITS;
    if (pos < STAGE_CAP) stage[pos] = s;
    else col[start + pos] = s;  // statistical never (cap = mean + 22 sigma)
  }
  __syncthreads();
  int lim = (size < STAGE_CAP) ? size : STAGE_CAP;
  for (int i = tid; i < lim; i += 256) col[start + i] = stage[i];  // coalesced
}

// one wave per node, one feature per lane; scalarized col reads,
// 16 independent gathers in flight (mean deg = 16 -> ~1 latency round).
__global__ void __launch_bounds__(256) aggregate_kernel(const float* __restrict__ xin,
                                                        const int* __restrict__ row_ptr,
                                                        const int* __restrict__ col,
                                                        float* __restrict__ outp, int n) {
  int gwave = (blockIdx.x * 256 + threadIdx.x) >> 6;
  int lane = threadIdx.x & 63;
  if (gwave >= n) return;
  int m = __builtin_amdgcn_readfirstlane(gwave);
  int start = row_ptr[m];
  int end = row_ptr[m + 1];
  float a[16];
#pragma unroll
  for (int i = 0; i < 16; ++i) a[i] = 0.f;
  int e = start;
  for (; e + 16 <= end; e += 16) {
    int c[16];
#pragma unroll
    for (int i = 0; i < 16; ++i) c[i] = col[e + i];
#pragma unroll
    for (int i = 0; i < 16; ++i) a[i] += xin[(size_t)c[i] * 64 + lane];
  }
  for (; e + 4 <= end; e += 4) {
    int c0 = col[e + 0], c1 = col[e + 1], c2 = col[e + 2], c3 = col[e + 3];
    a[0] += xin[(size_t)c0 * 64 + lane];
    a[1] += xin[(size_t)c1 * 64 + lane];
    a[2] += xin[(size_t)c2 * 64 + lane];
    a[3] += xin[(size_t)c3 * 64 + lane];
  }
  for (; e < end; ++e) a[0] += xin[(size_t)col[e] * 64 + lane];
#pragma unroll
  for (int i = 8; i > 0; i >>= 1)
#pragma unroll
    for (int j = 0; j < i; ++j) a[j] += a[j + i];
  int d = end - start;
  float inv = 1.0f / (float)((d > 0) ? d : 1);
  outp[(size_t)m * 64 + lane] = a[0] * inv;
}

// ---- register-tiled GEMM (R10, zero scalar loads in the inner loop) -------
#define GBM 128

__device__ __forceinline__ void gemm_phase(const float* __restrict__ M,
                                           const float* __restrict__ W,
                                           float (&Mt)[GBM][65], float (&Ws)[64][64],
                                           float4 (&acc)[8],
                                           int node0, int n, int tx, int ty, int t) {
  __syncthreads();  // previous phase's reads done before overwrite
#pragma unroll
  for (int i = 0; i < 8; ++i) {
    int f4 = i * 256 + t;          // 2048 float4 over [128][16]
    int r = f4 >> 4, c4 = f4 & 15;
    int nd = node0 + r;
    float4 v = make_float4(0.f, 0.f, 0.f, 0.f);
    if (nd < n) v = ((const float4*)(M + (size_t)nd * 64))[c4];
    Mt[r][c4 * 4 + 0] = v.x; Mt[r][c4 * 4 + 1] = v.y;
    Mt[r][c4 * 4 + 2] = v.z; Mt[r][c4 * 4 + 3] = v.w;
  }
#pragma unroll
  for (int i = 0; i < 4; ++i) {
    int f4 = i * 256 + t;          // 1024 float4 over [64][16]
    int k = f4 >> 4, c4 = f4 & 15;
    float4 v = ((const float4*)W)[f4];
    *(float4*)&Ws[k][c4 * 4] = v;
  }
  __syncthreads();
#pragma unroll 4
  for (int k = 0; k < 64; ++k) {
    float4 w4 = *(const float4*)&Ws[k][tx * 4];
    float a[8];
#pragma unroll
    for (int m = 0; m < 8; ++m) a[m] = Mt[ty * 8 + m][k];
#pragma unroll
    for (int m = 0; m < 8; ++m) {
      acc[m].x = fmaf(a[m], w4.x, acc[m].x);
      acc[m].y = fmaf(a[m], w4.y, acc[m].y);
      acc[m].z = fmaf(a[m], w4.z, acc[m].z);
      acc[m].w = fmaf(a[m], w4.w, acc[m].w);
    }
  }
}

// H = relu(A @ Wl + b + X @ Wr)
__global__ void __launch_bounds__(256) gemm_relu_kernel(const float* __restrict__ A,
                                                        const float* __restrict__ X,
                                                        const float* __restrict__ Wl,
                                                        const float* __restrict__ bias,
                                                        const float* __restrict__ Wr,
                                                        float* __restrict__ H, int n) {
  __shared__ float Mt[GBM][65];
  __shared__ float Ws[64][64];
  int t = threadIdx.x;
  int tx = t & 15, ty = t >> 4;
  int node0 = blockIdx.x * GBM;
  float4 bv = *(const float4*)(bias + tx * 4);
  float4 acc[8];
#pragma unroll
  for (int m = 0; m < 8; ++m) acc[m] = bv;
  gemm_phase(A, Wl, Mt, Ws, acc, node0, n, tx, ty, t);
  gemm_phase(X, Wr, Mt, Ws, acc, node0, n, tx, ty, t);
#pragma unroll
  for (int m = 0; m < 8; ++m) {
    int nd = node0 + ty * 8 + m;
    if (nd < n) {
      float4 v;
      v.x = fmaxf(acc[m].x, 0.f);
      v.y = fmaxf(acc[m].y, 0.f);
      v.z = fmaxf(acc[m].z, 0.f);
      v.w = fmaxf(acc[m].w, 0.f);
      ((float4*)(H + (size_t)nd * 64))[tx] = v;
    }
  }
}

// out = (A @ Wl + b + X @ Wr) @ Wc + bc; h2 never materialized.
__global__ void __launch_bounds__(256) gemm_cls_kernel(const float* __restrict__ A,
                                                       const float* __restrict__ X,
                                                       const float* __restrict__ Wl,
                                                       const float* __restrict__ bias,
                                                       const float* __restrict__ Wr,
                                                       const float* __restrict__ Wc,
                                                       const float* __restrict__ bc,
                                                       float* __restrict__ outp, int n) {
  __shared__ float Mt[GBM][65];
  __shared__ float Ws[64][64];
  int t = threadIdx.x;
  int tx = t & 15, ty = t >> 4;
  int node0 = blockIdx.x * GBM;
  float4 bv = *(const float4*)(bias + tx * 4);
  float4 acc[8];
#pragma unroll
  for (int m = 0; m < 8; ++m) acc[m] = bv;
  gemm_phase(A, Wl, Mt, Ws, acc, node0, n, tx, ty, t);
  gemm_phase(X, Wr, Mt, Ws, acc, node0, n, tx, ty, t);
  float2 wc0 = *(const float2*)(Wc + (tx * 4 + 0) * 2);
  float2 wc1 = *(const float2*)(Wc + (tx * 4 + 1) * 2);
  float2 wc2 = *(const float2*)(Wc + (tx * 4 + 2) * 2);
  float2 wc3 = *(const float2*)(Wc + (tx * 4 + 3) * 2);
  float b0 = bc[0], b1 = bc[1];
#pragma unroll
  for (int m = 0; m < 8; ++m) {
    float p0 = acc[m].x * wc0.x + acc[m].y * wc1.x + acc[m].z * wc2.x + acc[m].w * wc3.x;
    float p1 = acc[m].x * wc0.y + acc[m].y * wc1.y + acc[m].z * wc2.y + acc[m].w * wc3.y;
#pragma unroll
    for (int off = 1; off < 16; off <<= 1) {
      p0 += __shfl_xor(p0, off);
      p1 += __shfl_xor(p1, off);
    }
    if (tx == 0) {
      int nd = node0 + ty * 8 + m;
      if (nd < n) {
        float2 o;
        o.x = p0 + b0;
        o.y = p1 + b1;
        *(float2*)(outp + (size_t)nd * 2) = o;
      }
    }
  }
}

extern "C" void kernel_launch(void* const* d_in, const int* in_sizes, int n_in,
                              void* d_out, int out_size, void* d_ws, size_t ws_size,
                              hipStream_t stream) {
  const float* x   = (const float*)d_in[0];
  const int*   ei  = (const int*)d_in[1];
  const float* W1l = (const float*)d_in[2];
  const float* b1  = (const float*)d_in[3];
  const float* W1r = (const float*)d_in[4];
  const float* W2l = (const float*)d_in[5];
  const float* b2  = (const float*)d_in[6];
  const float* W2r = (const float*)d_in[7];
  const float* Wc  = (const float*)d_in[8];
  const float* bc  = (const float*)d_in[9];
  float* out = (float*)d_out;

  const int n  = in_sizes[0] / 64;   // 100000
  const int ne = in_sizes[1] / 2;    // 1600000
  const int* src = ei;
  const int* dst = ei + ne;

  const int B  = (n + BUCKET_NODES - 1) >> BUCKET_BITS;  // 196
  const int NB = (ne + EPB - 1) / EPB;                   // 196
  const int S  = B * NB;                                 // 38416
  const int nsb = (S + SCAN_BS - 1) / SCAN_BS;           // 38 (<=1024)

  char* ws = (char*)d_ws;
  size_t off = 0;
  auto carve = [&](size_t bytes) -> void* {
    void* p = ws + off;
    off += (bytes + 255) & ~(size_t)255;
    return p;
  };
  int* counts  = (int*)carve((size_t)S * 4);
  int* bsums   = (int*)carve((size_t)(nsb + 1) * 4);
  int* boffs   = (int*)carve((size_t)(nsb + 1) * 4);
  int* col     = (int*)carve((size_t)ne * 4);
  int* row_ptr = (int*)carve((size_t)(n + 1) * 4);
  float* m1    = (float*)carve((size_t)n * 64 * 4);  // mean buffer (both layers)
  float* h     = (float*)carve((size_t)n * 64 * 4);
  // arr (6.4MB) aliases m1 (25.6MB): arr lives from bucket_place to
  // csr_bucket; m1 is first written by aggregate, which runs after.
  int* arr     = (int*)m1;
  (void)ws_size;

  bucket_hist_kernel<<<NB, 256, 0, stream>>>(dst, counts, ne, B, NB);
  scan_a_inplace_kernel<<<nsb, SCAN_BS, 0, stream>>>(counts, bsums, S);
  scan_b_kernel<<<1, SCAN_BS, 0, stream>>>(bsums, boffs, nsb);
  bucket_place_kernel<<<NB, 256, 0, stream>>>(src, dst, counts, boffs, arr, ne, B, NB);
  csr_bucket_kernel<<<B, 256, 0, stream>>>(arr, counts, boffs, row_ptr, col, n, ne, B, NB);

  const int gtiles = (n + GBM - 1) / GBM;  // 782
  aggregate_kernel<<<(n * 64 + 255) / 256, 256, 0, stream>>>(x, row_ptr, col, m1, n);
  gemm_relu_kernel<<<gtiles, 256, 0, stream>>>(m1, x, W1l, b1, W1r, h, n);

  aggregate_kernel<<<(n * 64 + 255) / 256, 256, 0, stream>>>(h, row_ptr, col, m1, n);
  gemm_cls_kernel<<<gtiles, 256, 0, stream>>>(m1, h, W2l, b2, W2r, Wc, bc, out, n);
}

// Round 18
// 316.465 us; speedup vs baseline: 1.2664x; 1.0331x over previous
//
#include <hip/hip_runtime.h>

// ---------------------------------------------------------------------------
// GraphSAGE 2-layer (mean aggr) + linear classifier, fp32, N=100K, D=64, E=16N
// R15: de-starve the build grids. R14 accounting: agg 115 (measured floor) +
//  gemm <~60 leaves ~130-180us in 5 build kernels + gaps, yet the build moves
//  only ~50MB => latency-bound at 196 blocks (<1 block/CU) — same disease as
//  R7's lin layers. Fix: EPB 8192->2048 (hist/place 196->782 blocks),
//  BUCKET_BITS 9->8 (B=391: csr_bucket 196->391 blocks, LDS 23KB, 1
//  counter/thread scan). Per-bucket place runs shrink to ~21B: R12 measured
//  write density NEUTRAL, so free. Aggregate + R10 GEMMs untouched.
// ---------------------------------------------------------------------------

#define SCAN_BS 1024
#define BUCKET_BITS 8
#define BUCKET_NODES 256        // nodes per bucket
#define NBUCK_MAX 512           // >= B = ceil(100000/256) = 391
#define EPB 2048                // edges per block in hist/place passes
#define STAGE_CAP 5120          // bucket edges: mean 4096, sigma ~64 (+16s)

// --- K1: per-block bucket histogram -> counts[k * NB + b] (bucket-major) ---
__global__ void __launch_bounds__(256) bucket_hist_kernel(const int* __restrict__ dst,
                                                          int* __restrict__ counts,
                                                          int ne, int B, int NB) {
  __shared__ int hist[NBUCK_MAX];
  for (int k = threadIdx.x; k < B; k += 256) hist[k] = 0;
  __syncthreads();
  int base = blockIdx.x * EPB;
#pragma unroll 4
  for (int i = 0; i < EPB / 256; ++i) {
    int e = base + i * 256 + threadIdx.x;
    if (e < ne) atomicAdd(&hist[dst[e] >> BUCKET_BITS], 1);
  }
  __syncthreads();
  for (int k = threadIdx.x; k < B; k += 256) counts[k * NB + blockIdx.x] = hist[k];
}

// --- 2-level scan (in-place exclusive over counts) ---
__device__ __forceinline__ int block_scan_inclusive_1024(int v, int* wsums) {
  int lane = threadIdx.x & 63;
  int wid = threadIdx.x >> 6;
  int s = v;
#pragma unroll
  for (int off = 1; off < 64; off <<= 1) {
    int t = __shfl_up(s, off);
    if (lane >= off) s += t;
  }
  if (lane == 63) wsums[wid] = s;
  __syncthreads();
  if (wid == 0) {
    int ws = (lane < 16) ? wsums[lane] : 0;
#pragma unroll
    for (int off = 1; off < 16; off <<= 1) {
      int t = __shfl_up(ws, off);
      if (lane >= off) ws += t;
    }
    if (lane < 16) wsums[lane] = ws;
  }
  __syncthreads();
  if (wid > 0) s += wsums[wid - 1];
  return s;
}

__device__ __forceinline__ int block_scan_inclusive_256(int v, int* wsums4) {
  int lane = threadIdx.x & 63;
  int wid = threadIdx.x >> 6;  // 0..3
  int s = v;
#pragma unroll
  for (int off = 1; off < 64; off <<= 1) {
    int t = __shfl_up(s, off);
    if (lane >= off) s += t;
  }
  if (lane == 63) wsums4[wid] = s;
  __syncthreads();
  if (wid == 0) {
    int ws = (lane < 4) ? wsums4[lane] : 0;
#pragma unroll
    for (int off = 1; off < 4; off <<= 1) {
      int t = __shfl_up(ws, off);
      if (lane >= off) ws += t;
    }
    if (lane < 4) wsums4[lane] = ws;
  }
  __syncthreads();
  if (wid > 0) s += wsums4[wid - 1];
  return s;
}

__global__ void __launch_bounds__(SCAN_BS) scan_a_inplace_kernel(int* __restrict__ data,
                                                                 int* __restrict__ bsums,
                                                                 int S) {
  __shared__ int wsums[16];
  int i = blockIdx.x * SCAN_BS + threadIdx.x;
  int v = (i < S) ? data[i] : 0;
  int inc = block_scan_inclusive_1024(v, wsums);
  if (i < S) data[i] = inc - v;  // exclusive, block-local
  if (threadIdx.x == SCAN_BS - 1) bsums[blockIdx.x] = inc;
}

__global__ void __launch_bounds__(SCAN_BS) scan_b_kernel(const int* __restrict__ bsums,
                                                         int* __restrict__ boffs, int nb) {
  __shared__ int wsums[16];
  int v = ((int)threadIdx.x < nb) ? bsums[threadIdx.x] : 0;
  int inc = block_scan_inclusive_1024(v, wsums);
  if ((int)threadIdx.x < nb) boffs[threadIdx.x] = inc - v;
  if ((int)threadIdx.x == nb - 1) boffs[nb] = inc;
}

// --- K3: placement into bucket-grouped arr; LDS cursors; boffs folded in ---
__global__ void __launch_bounds__(256) bucket_place_kernel(const int* __restrict__ src,
                                                           const int* __restrict__ dst,
                                                           const int* __restrict__ counts,
                                                           const int* __restrict__ boffs,
                                                           int* __restrict__ arr,
                                                           int ne, int B, int NB) {
  __shared__ int cur[NBUCK_MAX];
  for (int k = threadIdx.x; k < B; k += 256) {
    int idx = k * NB + blockIdx.x;
    cur[k] = counts[idx] + boffs[idx >> 10];
  }
  __syncthreads();
  int base = blockIdx.x * EPB;
#pragma unroll 4
  for (int i = 0; i < EPB / 256; ++i) {
    int e = base + i * 256 + threadIdx.x;
    if (e < ne) {
      int d = dst[e];
      int k = d >> BUCKET_BITS;
      int pos = atomicAdd(&cur[k], 1);  // LDS atomic, absolute output slot
      arr[pos] = (src[e] << BUCKET_BITS) | (d & (BUCKET_NODES - 1));
    }
  }
}

// --- K4: per-bucket node-level CSR; LDS-staged coalesced col writes --------
__global__ void __launch_bounds__(256) csr_bucket_kernel(const int* __restrict__ arr,
                                                         const int* __restrict__ counts,
                                                         const int* __restrict__ boffs,
                                                         int* __restrict__ row_ptr,
                                                         int* __restrict__ col,
                                                         int n, int ne, int B, int NB) {
  __shared__ int hist[BUCKET_NODES];
  __shared__ int cur[BUCKET_NODES];
  __shared__ int stage[STAGE_CAP];
  __shared__ int wsums4[4];
  int k = blockIdx.x;
  int tid = threadIdx.x;
  int i0 = k * NB;
  int start = counts[i0] + boffs[i0 >> 10];
  int end;
  if (k + 1 < B) {
    int i1 = (k + 1) * NB;
    end = counts[i1] + boffs[i1 >> 10];
  } else {
    end = ne;
  }
  int size = end - start;
  hist[tid] = 0;  // BUCKET_NODES == blockDim == 256
  __syncthreads();
  for (int e = start + tid; e < end; e += 256)
    atomicAdd(&hist[arr[e] & (BUCKET_NODES - 1)], 1);
  __syncthreads();
  // exclusive scan of 256 counters: 1 per thread
  int v = hist[tid];
  int inc = block_scan_inclusive_256(v, wsums4);
  int e0 = inc - v;
  cur[tid] = e0;  // bucket-local cursor
  {
    int node = k * BUCKET_NODES + tid;
    if (node < n) row_ptr[node] = start + e0;
  }
  if (k == B - 1 && tid == 0) row_ptr[n] = ne;
  __syncthreads();
  for (int e = start + tid; e < end; e += 256) {
    int p = arr[e];
    int pos = atomicAdd(&cur[p & (BUCKET_NODES - 1)], 1);  // bucket-local slot
    int s = p >> BUCKET_BITS;
    if (pos < STAGE_CAP) stage[pos] = s;
    else col[start + pos] = s;  // statistical never (cap = mean + 16 sigma)
  }
  __syncthreads();
  int lim = (size < STAGE_CAP) ? size : STAGE_CAP;
  for (int i = tid; i < lim; i += 256) col[start + i] = stage[i];  // coalesced
}

// one wave per node, one feature per lane; scalarized col reads,
// 16 independent gathers in flight (mean deg = 16 -> ~1 latency round).
__global__ void __launch_bounds__(256) aggregate_kernel(const float* __restrict__ xin,
                                                        const int* __restrict__ row_ptr,
                                                        const int* __restrict__ col,
                                                        float* __restrict__ outp, int n) {
  int gwave = (blockIdx.x * 256 + threadIdx.x) >> 6;
  int lane = threadIdx.x & 63;
  if (gwave >= n) return;
  int m = __builtin_amdgcn_readfirstlane(gwave);
  int start = row_ptr[m];
  int end = row_ptr[m + 1];
  float a[16];
#pragma unroll
  for (int i = 0; i < 16; ++i) a[i] = 0.f;
  int e = start;
  for (; e + 16 <= end; e += 16) {
    int c[16];
#pragma unroll
    for (int i = 0; i < 16; ++i) c[i] = col[e + i];
#pragma unroll
    for (int i = 0; i < 16; ++i) a[i] += xin[(size_t)c[i] * 64 + lane];
  }
  for (; e + 4 <= end; e += 4) {
    int c0 = col[e + 0], c1 = col[e + 1], c2 = col[e + 2], c3 = col[e + 3];
    a[0] += xin[(size_t)c0 * 64 + lane];
    a[1] += xin[(size_t)c1 * 64 + lane];
    a[2] += xin[(size_t)c2 * 64 + lane];
    a[3] += xin[(size_t)c3 * 64 + lane];
  }
  for (; e < end; ++e) a[0] += xin[(size_t)col[e] * 64 + lane];
#pragma unroll
  for (int i = 8; i > 0; i >>= 1)
#pragma unroll
    for (int j = 0; j < i; ++j) a[j] += a[j + i];
  int d = end - start;
  float inv = 1.0f / (float)((d > 0) ? d : 1);
  outp[(size_t)m * 64 + lane] = a[0] * inv;
}

// ---- register-tiled GEMM (R10, zero scalar loads in the inner loop) -------
#define GBM 128

__device__ __forceinline__ void gemm_phase(const float* __restrict__ M,
                                           const float* __restrict__ W,
                                           float (&Mt)[GBM][65], float (&Ws)[64][64],
                                           float4 (&acc)[8],
                                           int node0, int n, int tx, int ty, int t) {
  __syncthreads();  // previous phase's reads done before overwrite
#pragma unroll
  for (int i = 0; i < 8; ++i) {
    int f4 = i * 256 + t;          // 2048 float4 over [128][16]
    int r = f4 >> 4, c4 = f4 & 15;
    int nd = node0 + r;
    float4 v = make_float4(0.f, 0.f, 0.f, 0.f);
    if (nd < n) v = ((const float4*)(M + (size_t)nd * 64))[c4];
    Mt[r][c4 * 4 + 0] = v.x; Mt[r][c4 * 4 + 1] = v.y;
    Mt[r][c4 * 4 + 2] = v.z; Mt[r][c4 * 4 + 3] = v.w;
  }
#pragma unroll
  for (int i = 0; i < 4; ++i) {
    int f4 = i * 256 + t;          // 1024 float4 over [64][16]
    int k = f4 >> 4, c4 = f4 & 15;
    float4 v = ((const float4*)W)[f4];
    *(float4*)&Ws[k][c4 * 4] = v;
  }
  __syncthreads();
#pragma unroll 4
  for (int k = 0; k < 64; ++k) {
    float4 w4 = *(const float4*)&Ws[k][tx * 4];
    float a[8];
#pragma unroll
    for (int m = 0; m < 8; ++m) a[m] = Mt[ty * 8 + m][k];
#pragma unroll
    for (int m = 0; m < 8; ++m) {
      acc[m].x = fmaf(a[m], w4.x, acc[m].x);
      acc[m].y = fmaf(a[m], w4.y, acc[m].y);
      acc[m].z = fmaf(a[m], w4.z, acc[m].z);
      acc[m].w = fmaf(a[m], w4.w, acc[m].w);
    }
  }
}

// H = relu(A @ Wl + b + X @ Wr)
__global__ void __launch_bounds__(256) gemm_relu_kernel(const float* __restrict__ A,
                                                        const float* __restrict__ X,
                                                        const float* __restrict__ Wl,
                                                        const float* __restrict__ bias,
                                                        const float* __restrict__ Wr,
                                                        float* __restrict__ H, int n) {
  __shared__ float Mt[GBM][65];
  __shared__ float Ws[64][64];
  int t = threadIdx.x;
  int tx = t & 15, ty = t >> 4;
  int node0 = blockIdx.x * GBM;
  float4 bv = *(const float4*)(bias + tx * 4);
  float4 acc[8];
#pragma unroll
  for (int m = 0; m < 8; ++m) acc[m] = bv;
  gemm_phase(A, Wl, Mt, Ws, acc, node0, n, tx, ty, t);
  gemm_phase(X, Wr, Mt, Ws, acc, node0, n, tx, ty, t);
#pragma unroll
  for (int m = 0; m < 8; ++m) {
    int nd = node0 + ty * 8 + m;
    if (nd < n) {
      float4 v;
      v.x = fmaxf(acc[m].x, 0.f);
      v.y = fmaxf(acc[m].y, 0.f);
      v.z = fmaxf(acc[m].z, 0.f);
      v.w = fmaxf(acc[m].w, 0.f);
      ((float4*)(H + (size_t)nd * 64))[tx] = v;
    }
  }
}

// out = (A @ Wl + b + X @ Wr) @ Wc + bc; h2 never materialized.
__global__ void __launch_bounds__(256) gemm_cls_kernel(const float* __restrict__ A,
                                                       const float* __restrict__ X,
                                                       const float* __restrict__ Wl,
                                                       const float* __restrict__ bias,
                                                       const float* __restrict__ Wr,
                                                       const float* __restrict__ Wc,
                                                       const float* __restrict__ bc,
                                                       float* __restrict__ outp, int n) {
  __shared__ float Mt[GBM][65];
  __shared__ float Ws[64][64];
  int t = threadIdx.x;
  int tx = t & 15, ty = t >> 4;
  int node0 = blockIdx.x * GBM;
  float4 bv = *(const float4*)(bias + tx * 4);
  float4 acc[8];
#pragma unroll
  for (int m = 0; m < 8; ++m) acc[m] = bv;
  gemm_phase(A, Wl, Mt, Ws, acc, node0, n, tx, ty, t);
  gemm_phase(X, Wr, Mt, Ws, acc, node0, n, tx, ty, t);
  float2 wc0 = *(const float2*)(Wc + (tx * 4 + 0) * 2);
  float2 wc1 = *(const float2*)(Wc + (tx * 4 + 1) * 2);
  float2 wc2 = *(const float2*)(Wc + (tx * 4 + 2) * 2);
  float2 wc3 = *(const float2*)(Wc + (tx * 4 + 3) * 2);
  float b0 = bc[0], b1 = bc[1];
#pragma unroll
  for (int m = 0; m < 8; ++m) {
    float p0 = acc[m].x * wc0.x + acc[m].y * wc1.x + acc[m].z * wc2.x + acc[m].w * wc3.x;
    float p1 = acc[m].x * wc0.y + acc[m].y * wc1.y + acc[m].z * wc2.y + acc[m].w * wc3.y;
#pragma unroll
    for (int off = 1; off < 16; off <<= 1) {
      p0 += __shfl_xor(p0, off);
      p1 += __shfl_xor(p1, off);
    }
    if (tx == 0) {
      int nd = node0 + ty * 8 + m;
      if (nd < n) {
        float2 o;
        o.x = p0 + b0;
        o.y = p1 + b1;
        *(float2*)(outp + (size_t)nd * 2) = o;
      }
    }
  }
}

extern "C" void kernel_launch(void* const* d_in, const int* in_sizes, int n_in,
                              void* d_out, int out_size, void* d_ws, size_t ws_size,
                              hipStream_t stream) {
  const float* x   = (const float*)d_in[0];
  const int*   ei  = (const int*)d_in[1];
  const float* W1l = (const float*)d_in[2];
  const float* b1  = (const float*)d_in[3];
  const float* W1r = (const float*)d_in[4];
  const float* W2l = (const float*)d_in[5];
  const float* b2  = (const float*)d_in[6];
  const float* W2r = (const float*)d_in[7];
  const float* Wc  = (const float*)d_in[8];
  const float* bc  = (const float*)d_in[9];
  float* out = (float*)d_out;

  const int n  = in_sizes[0] / 64;   // 100000
  const int ne = in_sizes[1] / 2;    // 1600000
  const int* src = ei;
  const int* dst = ei + ne;

  const int B  = (n + BUCKET_NODES - 1) >> BUCKET_BITS;  // 391
  const int NB = (ne + EPB - 1) / EPB;                   // 782
  const int S  = B * NB;                                 // 305762
  const int nsb = (S + SCAN_BS - 1) / SCAN_BS;           // 299 (<=1024)

  char* ws = (char*)d_ws;
  size_t off = 0;
  auto carve = [&](size_t bytes) -> void* {
    void* p = ws + off;
    off += (bytes + 255) & ~(size_t)255;
    return p;
  };
  int* counts  = (int*)carve((size_t)S * 4);
  int* bsums   = (int*)carve((size_t)(nsb + 1) * 4);
  int* boffs   = (int*)carve((size_t)(nsb + 1) * 4);
  int* col     = (int*)carve((size_t)ne * 4);
  int* row_ptr = (int*)carve((size_t)(n + 1) * 4);
  float* m1    = (float*)carve((size_t)n * 64 * 4);  // mean buffer (both layers)
  float* h     = (float*)carve((size_t)n * 64 * 4);
  // arr (6.4MB) aliases m1 (25.6MB): arr lives from bucket_place to
  // csr_bucket; m1 is first written by aggregate, which runs after.
  int* arr     = (int*)m1;
  (void)ws_size;

  bucket_hist_kernel<<<NB, 256, 0, stream>>>(dst, counts, ne, B, NB);
  scan_a_inplace_kernel<<<nsb, SCAN_BS, 0, stream>>>(counts, bsums, S);
  scan_b_kernel<<<1, SCAN_BS, 0, stream>>>(bsums, boffs, nsb);
  bucket_place_kernel<<<NB, 256, 0, stream>>>(src, dst, counts, boffs, arr, ne, B, NB);
  csr_bucket_kernel<<<B, 256, 0, stream>>>(arr, counts, boffs, row_ptr, col, n, ne, B, NB);

  const int gtiles = (n + GBM - 1) / GBM;  // 782
  aggregate_kernel<<<(n * 64 + 255) / 256, 256, 0, stream>>>(x, row_ptr, col, m1, n);
  gemm_relu_kernel<<<gtiles, 256, 0, stream>>>(m1, x, W1l, b1, W1r, h, n);

  aggregate_kernel<<<(n * 64 + 255) / 256, 256, 0, stream>>>(h, row_ptr, col, m1, n);
  gemm_cls_kernel<<<gtiles, 256, 0, stream>>>(m1, h, W2l, b2, W2r, Wc, bc, out, n);
}